// Round 17
// baseline (18.625 us; speedup 1.0000x reference)
//
#include <hip/hip_runtime.h>

#define LD 68  // fp32 LDS row stride: 272B
#define XP 72  // bf16 row pitch (ushorts): 144B

typedef float f32x4 __attribute__((ext_vector_type(4)));
typedef short s16x8 __attribute__((ext_vector_type(8)));
typedef unsigned long long u64;

__device__ __forceinline__ unsigned short f2bf(float f) {
  union { float f; unsigned int u; } v; v.f = f;
  const unsigned int r = (v.u + 0x7fffu + ((v.u >> 16) & 1u)) >> 16;
  return (unsigned short)r;
}
__device__ __forceinline__ float bf2f(unsigned short h) {
  union { unsigned int u; float f; } v; v.u = ((unsigned int)h) << 16;
  return v.f;
}

__global__ __launch_bounds__(512) void lagat_kernel(
    const float* __restrict__ adj,
    const float* __restrict__ feat_node,
    const int* __restrict__ idx,
    const int* __restrict__ head_ids,
    const int* __restrict__ tail_ids,
    const float* __restrict__ transform,
    const float* __restrict__ embed,
    const float* __restrict__ w1, const float* __restrict__ b1,
    const float* __restrict__ w2, const float* __restrict__ b2,
    const float* __restrict__ gamma1, const float* __restrict__ beta1,
    const float* __restrict__ gamma2, const float* __restrict__ beta2,
    float* __restrict__ out)
{
  // Ping-pong buffer B region; during setup it aliases Wt (34816B) + Tt.
  // Sb_B = bytes [0, 34816), CST_B = bytes [34816, 53248).
  __shared__ __align__(16) char regionB[53248];
  __shared__ __align__(16) float Sb_A[2][64][LD];            // state buf A
  __shared__ __align__(16) unsigned short CST_A[2][64][XP];  // (vc*S)^T buf A
  __shared__ __align__(16) float featb[64][LD];              // features
  __shared__ __align__(16) float Ib[64][LD];                 // init_feat (setup)
  __shared__ __align__(16) float prm[2][3][64];              // gamma,beta,bias
  __shared__ u64 adjbits[64];
  __shared__ u64 lev[2][3];                                  // BFS reach masks
  __shared__ float degs[64];

  float (*Wt)[64][LD] = reinterpret_cast<float(*)[64][LD]>(&regionB[0]);
  float (*Tt)[LD]     = reinterpret_cast<float(*)[LD]>(&regionB[34816]);
  float*          SbB  = reinterpret_cast<float*>(&regionB[0]);
  unsigned short* CSTB = reinterpret_cast<unsigned short*>(&regionB[34816]);
  float*          SbP[2]  = { &Sb_A[0][0][0], SbB };
  unsigned short* CSTP[2] = { &CST_A[0][0][0], CSTB };

  const int g = blockIdx.x, tid = threadIdx.x, nb = g * 64;
  const int wv = tid >> 6, lane = tid & 63;
  const int ech = wv >> 2, eslab = (wv & 3) * 16;
  const int ln15 = lane & 15, lg = lane >> 4, lg4 = lg * 4;
  const int iNode = eslab + ln15;

  // ---- P0: adj -> bit rows (ballot); init_feat, W^T, T^T, prm -> LDS ----
  {
#pragma unroll
    for (int rr = 0; rr < 8; ++rr) {
      const int row = wv * 8 + rr;
      const u64 b = __ballot(adj[(size_t)(nb + row) * 4096 + nb + lane] != 0.0f);
      if (lane == 0) adjbits[row] = b;
    }
  }
  {
    const int r = tid >> 3, c8 = (tid & 7) * 8;
    if (c8 < 32) {
      const float4* fs = (const float4*)&feat_node[(size_t)(nb + r) * 32 + c8];
      *(float4*)&Ib[r][c8]     = fs[0];
      *(float4*)&Ib[r][c8 + 4] = fs[1];
    } else {
      const float4* es = (const float4*)&embed[(size_t)idx[nb + r] * 32 + (c8 - 32)];
      *(float4*)&Ib[r][c8]     = es[0];
      *(float4*)&Ib[r][c8 + 4] = es[1];
    }
  }
  {
    // W transposed staging: 8192 elems, 16/thread
    const int base = tid * 16;
    const int m = base >> 12, off = base & 4095;
    const int k = off >> 6, c0 = off & 63;
    const float* src = (m ? w2 : w1) + (size_t)k * 64 + c0;
#pragma unroll
    for (int u = 0; u < 4; ++u) {
      const float4 v = *(const float4*)&src[u * 4];
      Wt[m][c0 + 4 * u][k]     = v.x;
      Wt[m][c0 + 4 * u + 1][k] = v.y;
      Wt[m][c0 + 4 * u + 2][k] = v.z;
      Wt[m][c0 + 4 * u + 3][k] = v.w;
    }
  }
  {
    // transform transposed staging: 4096 elems, 8/thread
    const int base = tid * 8;
    const int k = base >> 6, c0 = base & 63;
    const float* src = transform + (size_t)k * 64 + c0;
#pragma unroll
    for (int u = 0; u < 2; ++u) {
      const float4 v = *(const float4*)&src[u * 4];
      Tt[c0 + 4 * u][k]     = v.x;
      Tt[c0 + 4 * u + 1][k] = v.y;
      Tt[c0 + 4 * u + 2][k] = v.z;
      Tt[c0 + 4 * u + 3][k] = v.w;
    }
  }
  if (tid < 384) {
    const int a = tid >> 6, h = tid & 63;
    const float* s6 = (a == 0) ? gamma1 : (a == 1) ? beta1 : (a == 2) ? b1
                    : (a == 3) ? gamma2 : (a == 4) ? beta2 : b2;
    prm[a / 3][a % 3][h] = s6[h];
  }
  __syncthreads();

  const int hl = head_ids[g] - nb, tl = tail_ids[g] - nb;

  // ---- P1: degs + BFS (subset) ; W frags (all) ; feat MFMA (ech==0) ----
  if (tid < 64) {
    degs[tid] = (float)__popcll(adjbits[tid]);
  } else if (tid < 192) {
    const int c = (tid >> 6) - 1;     // chain 0 / 1
    const int root = c ? tl : hl;
    const u64 l0 = 1ull << root;
    const u64 l1 = l0 | adjbits[root];
    u64 cand = ((l1 >> lane) & 1ull) ? adjbits[lane] : 0ull;
#pragma unroll
    for (int m = 1; m < 64; m <<= 1) cand |= __shfl_xor(cand, m, 64);
    if (lane == 0) { lev[c][0] = l0; lev[c][1] = l1; lev[c][2] = l0 | cand; }
  }
  // W fragments from Wt (vector reads); adjacency frags from bits
  s16x8 wfh[8], afr[2];
  {
#pragma unroll
    for (int ct = 0; ct < 4; ++ct)
#pragma unroll
      for (int ks = 0; ks < 2; ++ks) {
        const float4 v0 = *(const float4*)&Wt[ech][ct * 16 + ln15][ks * 32 + lg * 8];
        const float4 v1 = *(const float4*)&Wt[ech][ct * 16 + ln15][ks * 32 + lg * 8 + 4];
        s16x8 h;
        h[0] = (short)f2bf(v0.x); h[1] = (short)f2bf(v0.y);
        h[2] = (short)f2bf(v0.z); h[3] = (short)f2bf(v0.w);
        h[4] = (short)f2bf(v1.x); h[5] = (short)f2bf(v1.y);
        h[6] = (short)f2bf(v1.z); h[7] = (short)f2bf(v1.w);
        wfh[ct * 2 + ks] = h;
      }
    const u64 abits = adjbits[iNode];
#pragma unroll
    for (int ks = 0; ks < 2; ++ks) {
      s16x8 a;
#pragma unroll
      for (int j = 0; j < 8; ++j)
        a[j] = (short)(((abits >> (ks * 32 + lg * 8 + j)) & 1ull) ? 0x3F80 : 0);
      afr[ks] = a;
    }
  }
  // feat = init @ transform via MFMA (waves 0-3 compute+write; dedup)
  if (ech == 0) {
    s16x8 ihf[2], ilf[2];
#pragma unroll
    for (int ks = 0; ks < 2; ++ks) {
      const float4 i0 = *(const float4*)&Ib[iNode][ks * 32 + lg * 8];
      const float4 i1 = *(const float4*)&Ib[iNode][ks * 32 + lg * 8 + 4];
      const float iv[8] = {i0.x, i0.y, i0.z, i0.w, i1.x, i1.y, i1.z, i1.w};
      s16x8 hh, ll;
#pragma unroll
      for (int j = 0; j < 8; ++j) {
        const unsigned short h = f2bf(iv[j]);
        hh[j] = (short)h;
        ll[j] = (short)f2bf(iv[j] - bf2f(h));
      }
      ihf[ks] = hh; ilf[ks] = ll;
    }
    f32x4 facc[4] = {{0,0,0,0},{0,0,0,0},{0,0,0,0},{0,0,0,0}};
#pragma unroll
    for (int ct = 0; ct < 4; ++ct)
#pragma unroll
      for (int ks = 0; ks < 2; ++ks) {
        const float4 t0 = *(const float4*)&Tt[ct * 16 + ln15][ks * 32 + lg * 8];
        const float4 t1 = *(const float4*)&Tt[ct * 16 + ln15][ks * 32 + lg * 8 + 4];
        s16x8 th;
        th[0] = (short)f2bf(t0.x); th[1] = (short)f2bf(t0.y);
        th[2] = (short)f2bf(t0.z); th[3] = (short)f2bf(t0.w);
        th[4] = (short)f2bf(t1.x); th[5] = (short)f2bf(t1.y);
        th[6] = (short)f2bf(t1.z); th[7] = (short)f2bf(t1.w);
        facc[ct] = __builtin_amdgcn_mfma_f32_16x16x32_bf16(th, ihf[ks], facc[ct], 0, 0, 0);
        facc[ct] = __builtin_amdgcn_mfma_f32_16x16x32_bf16(th, ilf[ks], facc[ct], 0, 0, 0);
      }
#pragma unroll
    for (int ct = 0; ct < 4; ++ct)
      *(float4*)&featb[iNode][ct * 16 + lg4] =
          make_float4(facc[ct][0], facc[ct][1], facc[ct][2], facc[ct][3]);
  }
  __syncthreads();

  // ---- P2: S init (buf A) + layer-0 ; preloads ; corr+CST init (buf A) ----
  {
    const int r = tid >> 3, c8 = (tid & 7) * 8;
#pragma unroll
    for (int u = 0; u < 2; ++u) {
      const float4 v = *(const float4*)&featb[r][c8 + 4 * u];
      *(float4*)&SbP[0][(0 * 64 + r) * LD + c8 + 4 * u] = v;
      *(float4*)&SbP[0][(1 * 64 + r) * LD + c8 + 4 * u] = v;
      *(float4*)&out[(size_t)(nb + r) * 256 + c8 + 4 * u] = v;
    }
  }
  const float dnv = 1.f / (degs[iNode] + 1e-8f);
  const int qrowE = ech ? hl : tl;
  u64 levCh[3];
#pragma unroll
  for (int k = 0; k < 3; ++k) levCh[k] = lev[ech][k];
  f32x4 ft4[4], qe4[4], bias4[4];
  float s_reg[4][4];     // this lane's S channels (E-slot layout), persistent
  float vc_reg;          // this node's current corr value
#pragma unroll
  for (int ct = 0; ct < 4; ++ct) {
    const int ebase = ((ct >> 1) << 5) + lg * 8 + ((ct & 1) << 2);
    ft4[ct] = *(const f32x4*)&featb[iNode][ebase];
    qe4[ct] = *(const f32x4*)&featb[qrowE][ct * 16 + lg4];
    bias4[ct] = *(const f32x4*)&prm[ech][2][ct * 16 + lg4];
  }
  {
    float v = 0.f;
#pragma unroll
    for (int ct = 0; ct < 4; ++ct) {
      const f32x4 sf = *(const f32x4*)&featb[iNode][ct * 16 + lg4];
#pragma unroll
      for (int r = 0; r < 4; ++r) { s_reg[ct][r] = sf[r]; v = fmaf(qe4[ct][r], sf[r], v); }
    }
    v += __shfl_xor(v, 16); v += __shfl_xor(v, 32);
    vc_reg = fabsf(v);
#pragma unroll
    for (int ct = 0; ct < 4; ++ct) {
      const int rbase = ((ct >> 1) << 5) + ((lg & 1) << 4) +
                        ((ct & 1) << 3) + ((lg >> 1) << 2);
#pragma unroll
      for (int r = 0; r < 4; ++r)
        CSTP[0][(ech * 64 + rbase + r) * XP + iNode] = f2bf(vc_reg * s_reg[ct][r]);
    }
  }
  __syncthreads();

  const int r8 = tid >> 3, cc8 = (tid & 7) * 8;   // layer-write map
  int cur = 0;

  for (int hop = 2; hop >= 0; --hop) {
    const int nxt = cur ^ 1;
    const float* curSb = SbP[cur];
    const unsigned short* curCST = CSTP[cur];
    float* nxtSb = SbP[nxt];
    unsigned short* nxtCST = CSTP[nxt];

    // deferred layer write (L = 2-hop); reads curSb (written last hop)
    if (hop != 2) {
      const int L = 2 - hop;
#pragma unroll
      for (int u = 0; u < 2; ++u) {
        const float4 a = *(const float4*)&curSb[(0 * 64 + r8) * LD + cc8 + 4 * u];
        const float4 b = *(const float4*)&curSb[(1 * 64 + r8) * LD + cc8 + 4 * u];
        *(float4*)&out[(size_t)(nb + r8) * 256 + (size_t)L * 64 + cc8 + 4 * u] =
            make_float4(a.x + b.x, a.y + b.y, a.z + b.z, a.w + b.w);
      }
    }

    // B (MFMA): slot (ct,r) = channel pi(ct*16+lg4+r) of node iNode
    f32x4 accB[4] = {{0,0,0,0},{0,0,0,0},{0,0,0,0},{0,0,0,0}};
#pragma unroll
    for (int ct = 0; ct < 4; ++ct)
#pragma unroll
      for (int ks = 0; ks < 2; ++ks) {
        const s16x8 ah =
            *(const s16x8*)&curCST[(ech * 64 + ct * 16 + ln15) * XP + ks * 32 + lg * 8];
        accB[ct] = __builtin_amdgcn_mfma_f32_16x16x32_bf16(ah, afr[ks], accB[ct], 0, 0, 0);
      }
    const float fB = (float)((levCh[hop] >> iNode) & 1ull);
    // epilogue: leaky/deg + LN + gamma/beta + f*feat (pi-channel params)
    float x[4][4];
    {
      float smm = 0.f, s2m = 0.f;
#pragma unroll
      for (int ct = 0; ct < 4; ++ct)
#pragma unroll
        for (int r = 0; r < 4; ++r) {
          float z = accB[ct][r];
          z = (z > 0.f) ? z : 0.01f * z;   // leaky_relu slope 0.01
          z *= dnv;
          x[ct][r] = z; smm += z; s2m = fmaf(z, z, s2m);
        }
      smm += __shfl_xor(smm, 16); smm += __shfl_xor(smm, 32);
      s2m += __shfl_xor(s2m, 16); s2m += __shfl_xor(s2m, 32);
      const float mu = smm * 0.015625f;
      const float var = fmaxf(s2m * 0.015625f - mu * mu, 0.f);
      const float rstd = rsqrtf(var + 1e-5f);
#pragma unroll
      for (int ct = 0; ct < 4; ++ct) {
        const int ebase = ((ct >> 1) << 5) + lg * 8 + ((ct & 1) << 2);
        const f32x4 ga4 = *(const f32x4*)&prm[ech][0][ebase];
        const f32x4 be4 = *(const f32x4*)&prm[ech][1][ebase];
#pragma unroll
        for (int r = 0; r < 4; ++r)
          x[ct][r] = fmaf(fB, ft4[ct][r], ga4[r] * (x[ct][r] - mu) * rstd + be4[r]);
      }
    }
    // pack E fragments in-register (slot channel == frag channel by pi)
    s16x8 xh2[2], xl2[2];
#pragma unroll
    for (int ks = 0; ks < 2; ++ks) {
      s16x8 hh, ll;
#pragma unroll
      for (int j = 0; j < 8; ++j) {
        const float xv = x[2 * ks + (j >> 2)][j & 3];
        const unsigned short h = f2bf(xv);
        hh[j] = (short)h;
        ll[j] = (short)f2bf(xv - bf2f(h));
      }
      xh2[ks] = hh; xl2[ks] = ll;
    }
    // E (MFMA): (X@W)^T; relu + corr dot, all in registers
    f32x4 accE[4];
#pragma unroll
    for (int ct = 0; ct < 4; ++ct) {
      accE[ct] = bias4[ct];
#pragma unroll
      for (int ks = 0; ks < 2; ++ks) {
        accE[ct] = __builtin_amdgcn_mfma_f32_16x16x32_bf16(wfh[ct*2+ks], xh2[ks], accE[ct], 0, 0, 0);
        accE[ct] = __builtin_amdgcn_mfma_f32_16x16x32_bf16(wfh[ct*2+ks], xl2[ks], accE[ct], 0, 0, 0);
      }
    }
    float v = 0.f;
    float snew[4][4];
#pragma unroll
    for (int ct = 0; ct < 4; ++ct)
#pragma unroll
      for (int r = 0; r < 4; ++r) {
        const float sv = fmaxf(accE[ct][r], 0.f);
        snew[ct][r] = sv;
        v = fmaf(qe4[ct][r], sv, v);
      }
    v += __shfl_xor(v, 16); v += __shfl_xor(v, 32);
    const bool upd = ((levCh[hop] >> iNode) & 1ull) != 0;
    // conditional register update (branch-free), then unconditional writes
#pragma unroll
    for (int ct = 0; ct < 4; ++ct)
#pragma unroll
      for (int r = 0; r < 4; ++r)
        s_reg[ct][r] = upd ? snew[ct][r] : s_reg[ct][r];
    vc_reg = upd ? fabsf(v) : vc_reg;

#pragma unroll
    for (int ct = 0; ct < 4; ++ct) {
      *(float4*)&nxtSb[(ech * 64 + iNode) * LD + ct * 16 + lg4] =
          make_float4(s_reg[ct][0], s_reg[ct][1], s_reg[ct][2], s_reg[ct][3]);
      if (hop) {
        const int rbase = ((ct >> 1) << 5) + ((lg & 1) << 4) +
                          ((ct & 1) << 3) + ((lg >> 1) << 2);
#pragma unroll
        for (int r = 0; r < 4; ++r)
          nxtCST[(ech * 64 + rbase + r) * XP + iNode] = f2bf(vc_reg * s_reg[ct][r]);
      }
    }
    __syncthreads();
    cur = nxt;
  }

  // final layer 3 write (reads the buffer written by hop 0)
  {
    const float* curSb = SbP[cur];
#pragma unroll
    for (int u = 0; u < 2; ++u) {
      const float4 a = *(const float4*)&curSb[(0 * 64 + r8) * LD + cc8 + 4 * u];
      const float4 b = *(const float4*)&curSb[(1 * 64 + r8) * LD + cc8 + 4 * u];
      *(float4*)&out[(size_t)(nb + r8) * 256 + 192 + cc8 + 4 * u] =
          make_float4(a.x + b.x, a.y + b.y, a.z + b.z, a.w + b.w);
    }
  }
}

extern "C" void kernel_launch(void* const* d_in, const int* in_sizes, int n_in,
                              void* d_out, int out_size, void* d_ws, size_t ws_size,
                              hipStream_t stream) {
  const float* adj       = (const float*)d_in[0];
  const float* feat_node = (const float*)d_in[1];
  const int*   idx       = (const int*)d_in[2];
  const int*   head_ids  = (const int*)d_in[3];
  const int*   tail_ids  = (const int*)d_in[4];
  // d_in[5] = graph_indices (implied by block structure, unused)
  const float* transform = (const float*)d_in[6];
  const float* embed     = (const float*)d_in[7];
  const float* w1v    = (const float*)d_in[8];
  const float* b1v    = (const float*)d_in[9];
  const float* w2v    = (const float*)d_in[10];
  const float* b2v    = (const float*)d_in[11];
  const float* gamma1 = (const float*)d_in[12];
  const float* beta1  = (const float*)d_in[13];
  const float* gamma2 = (const float*)d_in[14];
  const float* beta2  = (const float*)d_in[15];

  lagat_kernel<<<64, 512, 0, stream>>>(adj, feat_node, idx, head_ids, tail_ids,
      transform, embed, w1v, b1v, w2v, b2v, gamma1, beta1, gamma2, beta2,
      (float*)d_out);
}